// Round 8
// baseline (121.376 us; speedup 1.0000x reference)
//
#include <hip/hip_runtime.h>
#include <cmath>

// B=64, S=2048, H=1024 fp32 attention + combine linear.
// lstm_output (512 MiB) dominates -> single-pass online softmax, read once.
// Round 8: NSPLIT 16->32 (2048 blocks, 8 sequential per CU-slot) for deeper
// tail smoothing -- templated on NSPLIT with runtime ws_size check (falls
// back to 16 if the 8.7 MB partial buffer doesn't fit). Pipeline structure
// unchanged (per-wave free-run, depth-3 prefetch, counted vmcnt, 4-slot ring).

namespace {
constexpr int B = 64;
constexpr int S = 2048;
constexpr int H = 1024;                // floats per row (256 float4)
constexpr int TR = 4;                  // rows per tile (one per wave)
constexpr int TF4 = TR * 256;          // float4 per tile buffer
constexpr int NBUF = 4;                // 64 KB LDS, per-wave 4-slot ring
constexpr int PSTRIDE = H + 4;         // floats per partial record
}

// ---- stage one row (4 KB) into LDS: 4 x global_load_lds(16B/lane) ----------
__device__ __forceinline__ void stage_row(const float4* grow, float4* lrow,
                                          int lane)
{
#pragma unroll
    for (int it = 0; it < 4; ++it) {
        __builtin_amdgcn_global_load_lds(
            (__attribute__((address_space(1))) void*)(grow + it * 64 + lane),
            (__attribute__((address_space(3))) void*)(lrow + it * 64),
            16, 0, 0);   // LDS dest = wave-uniform base + lane*16 (linear)
    }
}

// One pipeline step for row index T (wave-local). WN = vmcnt wait literal.
#define P1_ITER(T, WN) do {                                                    \
    asm volatile("s_waitcnt vmcnt(" #WN ")" ::: "memory");                     \
    const float4* r = lbuf + ((T) & 3) * TF4 + w * 256;                        \
    float4 a0 = r[lane], a1 = r[lane + 64],                                    \
           a2 = r[lane + 128], a3 = r[lane + 192];                             \
    asm volatile("s_waitcnt lgkmcnt(4)" ::: "memory");                         \
    __builtin_amdgcn_sched_barrier(0);                                         \
    if ((T) + 3 < NT)                                                          \
        stage_row(gbase + (size_t)(((T) + 3) * TR + w) * 256,                  \
                  lbuf + (((T) + 3) & 3) * TF4 + w * 256, lane);               \
    float d = 0.f, e = 0.f;                                                    \
    d = fmaf(a0.x, hv[0].x, d); d = fmaf(a0.y, hv[0].y, d);                    \
    d = fmaf(a0.z, hv[0].z, d); d = fmaf(a0.w, hv[0].w, d);                    \
    e = fmaf(a1.x, hv[1].x, e); e = fmaf(a1.y, hv[1].y, e);                    \
    e = fmaf(a1.z, hv[1].z, e); e = fmaf(a1.w, hv[1].w, e);                    \
    d = fmaf(a2.x, hv[2].x, d); d = fmaf(a2.y, hv[2].y, d);                    \
    d = fmaf(a2.z, hv[2].z, d); d = fmaf(a2.w, hv[2].w, d);                    \
    e = fmaf(a3.x, hv[3].x, e); e = fmaf(a3.y, hv[3].y, e);                    \
    e = fmaf(a3.z, hv[3].z, e); e = fmaf(a3.w, hv[3].w, e);                    \
    d += e;                                                                    \
    _Pragma("unroll")                                                          \
    for (int o = 32; o >= 1; o >>= 1) d += __shfl_xor(d, o);                   \
    const float mx = fmaxf(m, d);                                              \
    const float sc = __expf(m - mx);   /* exp(-inf)=0 on first row */          \
    const float p  = __expf(d - mx);                                           \
    l = fmaf(l, sc, p);                                                        \
    m = mx;                                                                    \
    acc[0].x = fmaf(acc[0].x, sc, p * a0.x);                                   \
    acc[0].y = fmaf(acc[0].y, sc, p * a0.y);                                   \
    acc[0].z = fmaf(acc[0].z, sc, p * a0.z);                                   \
    acc[0].w = fmaf(acc[0].w, sc, p * a0.w);                                   \
    acc[1].x = fmaf(acc[1].x, sc, p * a1.x);                                   \
    acc[1].y = fmaf(acc[1].y, sc, p * a1.y);                                   \
    acc[1].z = fmaf(acc[1].z, sc, p * a1.z);                                   \
    acc[1].w = fmaf(acc[1].w, sc, p * a1.w);                                   \
    acc[2].x = fmaf(acc[2].x, sc, p * a2.x);                                   \
    acc[2].y = fmaf(acc[2].y, sc, p * a2.y);                                   \
    acc[2].z = fmaf(acc[2].z, sc, p * a2.z);                                   \
    acc[2].w = fmaf(acc[2].w, sc, p * a2.w);                                   \
    acc[3].x = fmaf(acc[3].x, sc, p * a3.x);                                   \
    acc[3].y = fmaf(acc[3].y, sc, p * a3.y);                                   \
    acc[3].z = fmaf(acc[3].z, sc, p * a3.z);                                   \
    acc[3].w = fmaf(acc[3].w, sc, p * a3.w);                                   \
} while (0)

// ---------------- Pass 1: fused scores + online softmax + weighted sum ------
template <int NS>
__global__ __launch_bounds__(256, 2) void attn_pass1(
    const float* __restrict__ lstm,
    const float* __restrict__ hidden,
    float* __restrict__ ws)
{
    constexpr int CHUNK = S / NS;
    constexpr int NT = CHUNK / TR;

    __shared__ float4 lbuf[NBUF * TF4];    // 64 KB
    __shared__ float red_m[4];
    __shared__ float red_l[4];

    const int c    = blockIdx.x;
    const int b    = blockIdx.y;
    const int tid  = threadIdx.x;
    const int w    = tid >> 6;
    const int lane = tid & 63;

    const float4* hid4 = reinterpret_cast<const float4*>(hidden + (size_t)b * H);
    float4 hv[4];
#pragma unroll
    for (int j = 0; j < 4; ++j) hv[j] = hid4[lane + 64 * j];

    const float4* gbase =
        reinterpret_cast<const float4*>(lstm + ((size_t)b * S + c * CHUNK) * H);
    // wave w's row of tile t: gbase + (t*TR + w)*256

    float m = -INFINITY, l = 0.0f;
    float4 acc[4];
#pragma unroll
    for (int j = 0; j < 4; ++j) acc[j] = make_float4(0.f, 0.f, 0.f, 0.f);

    // prologue: 3 rows in flight per wave (12 loads)
    stage_row(gbase + (size_t)(0 * TR + w) * 256, lbuf + 0 * TF4 + w * 256, lane);
    stage_row(gbase + (size_t)(1 * TR + w) * 256, lbuf + 1 * TF4 + w * 256, lane);
    stage_row(gbase + (size_t)(2 * TR + w) * 256, lbuf + 2 * TF4 + w * 256, lane);

    for (int t = 0; t < NT - 2; ++t) P1_ITER(t, 8);   // steady: 2 rows in flight
    P1_ITER(NT - 2, 4);
    P1_ITER(NT - 1, 0);

    // ---- combine the 4 waves; reuse lbuf (all staging drained) ------------
    __syncthreads();
    if (lane == 0) { red_m[w] = m; red_l[w] = l; }
    __syncthreads();

    const float M = fmaxf(fmaxf(red_m[0], red_m[1]), fmaxf(red_m[2], red_m[3]));
    const float sc = __expf(m - M);
    float4* accbuf = lbuf;
#pragma unroll
    for (int j = 0; j < 4; ++j) {
        float4 a = acc[j];
        accbuf[w * 256 + lane + 64 * j] =
            make_float4(a.x * sc, a.y * sc, a.z * sc, a.w * sc);
    }
    __syncthreads();

    const float L = red_l[0] * __expf(red_m[0] - M)
                  + red_l[1] * __expf(red_m[1] - M)
                  + red_l[2] * __expf(red_m[2] - M)
                  + red_l[3] * __expf(red_m[3] - M);

    float* part = ws + (size_t)(b * NS + c) * PSTRIDE;
    float4 s4 = accbuf[tid];
    {
        float4 t1 = accbuf[256 + tid];
        float4 t2 = accbuf[512 + tid];
        float4 t3 = accbuf[768 + tid];
        s4.x += t1.x + t2.x + t3.x;
        s4.y += t1.y + t2.y + t3.y;
        s4.z += t1.z + t2.z + t3.z;
        s4.w += t1.w + t2.w + t3.w;
    }
    reinterpret_cast<float4*>(part)[tid] = s4;
    if (tid == 0) { part[H] = M; part[H + 1] = L; }
}

// ---------------- Pass 2: merge NS partials per batch -----------------------
template <int NS>
__global__ __launch_bounds__(256) void attn_pass2(
    const float* __restrict__ ws, float* __restrict__ attn)
{
    const int b   = blockIdx.x;
    const int tid = threadIdx.x;

    __shared__ float sm[NS];
    __shared__ float sl[NS];
    if (tid < NS) {
        const float* part = ws + (size_t)(b * NS + tid) * PSTRIDE;
        sm[tid] = part[H];
        sl[tid] = part[H + 1];
    }
    __syncthreads();

    float M = -INFINITY;
#pragma unroll
    for (int i = 0; i < NS; ++i) M = fmaxf(M, sm[i]);
    float L = 0.0f;
#pragma unroll
    for (int i = 0; i < NS; ++i) L = fmaf(sl[i], __expf(sm[i] - M), L);
    const float inv = 1.0f / L;

    float4 a = make_float4(0.f, 0.f, 0.f, 0.f);
#pragma unroll
    for (int i = 0; i < NS; ++i) {
        const float f = __expf(sm[i] - M);
        float4 v = reinterpret_cast<const float4*>(
            ws + (size_t)(b * NS + i) * PSTRIDE)[tid];
        a.x = fmaf(v.x, f, a.x);
        a.y = fmaf(v.y, f, a.y);
        a.z = fmaf(v.z, f, a.z);
        a.w = fmaf(v.w, f, a.w);
    }
    reinterpret_cast<float4*>(attn)[(size_t)b * (H / 4) + tid] =
        make_float4(a.x * inv, a.y * inv, a.z * inv, a.w * inv);
}

// ---------------- Pass 3: out = [hidden, attn] @ W^T + bias -----------------
// Grid (H/16, 8): wave = 2 features, block handles 8 batches -> 512 blocks,
// all CUs busy; W re-read 8x (64 MB, L3-absorbed). Coalesced X reads.
__global__ __launch_bounds__(512) void attn_pass3(
    const float* __restrict__ hidden,
    const float* __restrict__ W,        // [H, 2H] row-major
    const float* __restrict__ bias,
    const float* __restrict__ attn,     // [B, H]
    float* __restrict__ out)            // [B, H]
{
    const int tid  = threadIdx.x;
    const int wid  = tid >> 6;
    const int lane = tid & 63;
    const int o0   = blockIdx.x * 16 + wid * 2;
    const int o1   = o0 + 1;
    const int blo  = blockIdx.y * (B / 8);
    const int bhi  = blo + (B / 8);

    const float4* W0 = reinterpret_cast<const float4*>(W + (size_t)o0 * (2 * H));
    const float4* W1 = reinterpret_cast<const float4*>(W + (size_t)o1 * (2 * H));
    float4 w0[8], w1[8];
#pragma unroll
    for (int j = 0; j < 8; ++j) w0[j] = W0[lane + 64 * j];
#pragma unroll
    for (int j = 0; j < 8; ++j) w1[j] = W1[lane + 64 * j];
    const float b0 = bias[o0];
    const float b1 = bias[o1];

    for (int b = blo; b < bhi; ++b) {
        const float4* h4 = reinterpret_cast<const float4*>(hidden + (size_t)b * H);
        const float4* a4 = reinterpret_cast<const float4*>(attn + (size_t)b * H);
        float s0 = 0.f, s1 = 0.f, t0 = 0.f, t1 = 0.f;
#pragma unroll
        for (int j = 0; j < 4; ++j) {
            float4 x = h4[lane + 64 * j];
            s0 = fmaf(x.x, w0[j].x, s0); s0 = fmaf(x.y, w0[j].y, s0);
            s0 = fmaf(x.z, w0[j].z, s0); s0 = fmaf(x.w, w0[j].w, s0);
            s1 = fmaf(x.x, w1[j].x, s1); s1 = fmaf(x.y, w1[j].y, s1);
            s1 = fmaf(x.z, w1[j].z, s1); s1 = fmaf(x.w, w1[j].w, s1);
            float4 y = a4[lane + 64 * j];
            t0 = fmaf(y.x, w0[j + 4].x, t0); t0 = fmaf(y.y, w0[j + 4].y, t0);
            t0 = fmaf(y.z, w0[j + 4].z, t0); t0 = fmaf(y.w, w0[j + 4].w, t0);
            t1 = fmaf(y.x, w1[j + 4].x, t1); t1 = fmaf(y.y, w1[j + 4].y, t1);
            t1 = fmaf(y.z, w1[j + 4].z, t1); t1 = fmaf(y.w, w1[j + 4].w, t1);
        }
        s0 += t0; s1 += t1;
#pragma unroll
        for (int off = 32; off >= 1; off >>= 1) {
            s0 += __shfl_xor(s0, off);
            s1 += __shfl_xor(s1, off);
        }
        if (lane == 0) {
            out[(size_t)b * H + o0] = s0 + b0;
            out[(size_t)b * H + o1] = s1 + b1;
        }
    }
}

extern "C" void kernel_launch(void* const* d_in, const int* in_sizes, int n_in,
                              void* d_out, int out_size, void* d_ws, size_t ws_size,
                              hipStream_t stream)
{
    const float* lstm   = (const float*)d_in[0];  // [B,S,H]
    const float* hidden = (const float*)d_in[1];  // [B,H]
    const float* W      = (const float*)d_in[2];  // [H,2H]
    const float* bias   = (const float*)d_in[3];  // [H]
    float* out = (float*)d_out;                   // [B,H]
    float* ws  = (float*)d_ws;

    const size_t need32 =
        ((size_t)32 * B * PSTRIDE + (size_t)B * H) * sizeof(float);  // ~8.7 MB

    if (ws_size >= need32) {
        float* attn = ws + (size_t)32 * B * PSTRIDE;
        attn_pass1<32><<<dim3(32, B), 256, 0, stream>>>(lstm, hidden, ws);
        attn_pass2<32><<<dim3(B), 256, 0, stream>>>(ws, attn);
        attn_pass3<<<dim3(H / 16, 8), 512, 0, stream>>>(hidden, W, bias, attn, out);
    } else {
        float* attn = ws + (size_t)16 * B * PSTRIDE;
        attn_pass1<16><<<dim3(16, B), 256, 0, stream>>>(lstm, hidden, ws);
        attn_pass2<16><<<dim3(B), 256, 0, stream>>>(ws, attn);
        attn_pass3<<<dim3(H / 16, 8), 512, 0, stream>>>(hidden, W, bias, attn, out);
    }
}

// Round 9
// 115.071 us; speedup vs baseline: 1.0548x; 1.0548x over previous
//
#include <hip/hip_runtime.h>
#include <cmath>

// B=64, S=2048, H=1024 fp32 attention + combine linear.
// lstm_output (512 MiB) dominates -> single-pass online softmax, read once.
// Round 9: pass1/pass3 reverted to round-7 exact (best known: NSPLIT=16,
// per-wave free-run depth-3 counted-vmcnt pipeline, 4-slot LDS ring;
// pass3 512 blocks x 8 batches). Pass2 parallelized 4x: grid (B,4), each
// block merges one quarter of one batch's attn vector (partials L2/L3-hot,
// latency-bound -> scales with blocks).

namespace {
constexpr int B = 64;
constexpr int S = 2048;
constexpr int H = 1024;                // floats per row (256 float4)
constexpr int NSPLIT = 16;             // 1024 blocks -> 4 per CU-slot queue
constexpr int CHUNK = S / NSPLIT;      // 128 rows per block
constexpr int TR = 4;                  // rows per tile (one per wave)
constexpr int NT = CHUNK / TR;         // 32 tiles per block
constexpr int TF4 = TR * 256;          // float4 per tile buffer
constexpr int NBUF = 4;                // 64 KB LDS, per-wave 4-slot ring
constexpr int PSTRIDE = H + 4;         // floats per partial record
constexpr size_t ATTN_OFF = (size_t)B * NSPLIT * PSTRIDE;  // floats
}

// ---- stage one row (4 KB) into LDS: 4 x global_load_lds(16B/lane) ----------
__device__ __forceinline__ void stage_row(const float4* grow, float4* lrow,
                                          int lane)
{
#pragma unroll
    for (int it = 0; it < 4; ++it) {
        __builtin_amdgcn_global_load_lds(
            (__attribute__((address_space(1))) void*)(grow + it * 64 + lane),
            (__attribute__((address_space(3))) void*)(lrow + it * 64),
            16, 0, 0);   // LDS dest = wave-uniform base + lane*16 (linear)
    }
}

// One pipeline step for row index T (wave-local). WN = vmcnt wait literal.
#define P1_ITER(T, WN) do {                                                    \
    asm volatile("s_waitcnt vmcnt(" #WN ")" ::: "memory");                     \
    const float4* r = lbuf + ((T) & 3) * TF4 + w * 256;                        \
    float4 a0 = r[lane], a1 = r[lane + 64],                                    \
           a2 = r[lane + 128], a3 = r[lane + 192];                             \
    asm volatile("s_waitcnt lgkmcnt(4)" ::: "memory");                         \
    __builtin_amdgcn_sched_barrier(0);                                         \
    if ((T) + 3 < NT)                                                          \
        stage_row(gbase + (size_t)(((T) + 3) * TR + w) * 256,                  \
                  lbuf + (((T) + 3) & 3) * TF4 + w * 256, lane);               \
    float d = 0.f, e = 0.f;                                                    \
    d = fmaf(a0.x, hv[0].x, d); d = fmaf(a0.y, hv[0].y, d);                    \
    d = fmaf(a0.z, hv[0].z, d); d = fmaf(a0.w, hv[0].w, d);                    \
    e = fmaf(a1.x, hv[1].x, e); e = fmaf(a1.y, hv[1].y, e);                    \
    e = fmaf(a1.z, hv[1].z, e); e = fmaf(a1.w, hv[1].w, e);                    \
    d = fmaf(a2.x, hv[2].x, d); d = fmaf(a2.y, hv[2].y, d);                    \
    d = fmaf(a2.z, hv[2].z, d); d = fmaf(a2.w, hv[2].w, d);                    \
    e = fmaf(a3.x, hv[3].x, e); e = fmaf(a3.y, hv[3].y, e);                    \
    e = fmaf(a3.z, hv[3].z, e); e = fmaf(a3.w, hv[3].w, e);                    \
    d += e;                                                                    \
    _Pragma("unroll")                                                          \
    for (int o = 32; o >= 1; o >>= 1) d += __shfl_xor(d, o);                   \
    const float mx = fmaxf(m, d);                                              \
    const float sc = __expf(m - mx);   /* exp(-inf)=0 on first row */          \
    const float p  = __expf(d - mx);                                           \
    l = fmaf(l, sc, p);                                                        \
    m = mx;                                                                    \
    acc[0].x = fmaf(acc[0].x, sc, p * a0.x);                                   \
    acc[0].y = fmaf(acc[0].y, sc, p * a0.y);                                   \
    acc[0].z = fmaf(acc[0].z, sc, p * a0.z);                                   \
    acc[0].w = fmaf(acc[0].w, sc, p * a0.w);                                   \
    acc[1].x = fmaf(acc[1].x, sc, p * a1.x);                                   \
    acc[1].y = fmaf(acc[1].y, sc, p * a1.y);                                   \
    acc[1].z = fmaf(acc[1].z, sc, p * a1.z);                                   \
    acc[1].w = fmaf(acc[1].w, sc, p * a1.w);                                   \
    acc[2].x = fmaf(acc[2].x, sc, p * a2.x);                                   \
    acc[2].y = fmaf(acc[2].y, sc, p * a2.y);                                   \
    acc[2].z = fmaf(acc[2].z, sc, p * a2.z);                                   \
    acc[2].w = fmaf(acc[2].w, sc, p * a2.w);                                   \
    acc[3].x = fmaf(acc[3].x, sc, p * a3.x);                                   \
    acc[3].y = fmaf(acc[3].y, sc, p * a3.y);                                   \
    acc[3].z = fmaf(acc[3].z, sc, p * a3.z);                                   \
    acc[3].w = fmaf(acc[3].w, sc, p * a3.w);                                   \
} while (0)

// ---------------- Pass 1: fused scores + online softmax + weighted sum ------
__global__ __launch_bounds__(256, 2) void attn_pass1(
    const float* __restrict__ lstm,
    const float* __restrict__ hidden,
    float* __restrict__ ws)
{
    __shared__ float4 lbuf[NBUF * TF4];    // 64 KB
    __shared__ float red_m[4];
    __shared__ float red_l[4];

    const int c    = blockIdx.x;
    const int b    = blockIdx.y;
    const int tid  = threadIdx.x;
    const int w    = tid >> 6;
    const int lane = tid & 63;

    const float4* hid4 = reinterpret_cast<const float4*>(hidden + (size_t)b * H);
    float4 hv[4];
#pragma unroll
    for (int j = 0; j < 4; ++j) hv[j] = hid4[lane + 64 * j];

    const float4* gbase =
        reinterpret_cast<const float4*>(lstm + ((size_t)b * S + c * CHUNK) * H);
    // wave w's row of tile t: gbase + (t*TR + w)*256

    float m = -INFINITY, l = 0.0f;
    float4 acc[4];
#pragma unroll
    for (int j = 0; j < 4; ++j) acc[j] = make_float4(0.f, 0.f, 0.f, 0.f);

    // prologue: 3 rows in flight per wave (12 loads)
    stage_row(gbase + (size_t)(0 * TR + w) * 256, lbuf + 0 * TF4 + w * 256, lane);
    stage_row(gbase + (size_t)(1 * TR + w) * 256, lbuf + 1 * TF4 + w * 256, lane);
    stage_row(gbase + (size_t)(2 * TR + w) * 256, lbuf + 2 * TF4 + w * 256, lane);

    for (int t = 0; t < NT - 2; ++t) P1_ITER(t, 8);   // steady: 2 rows in flight
    P1_ITER(NT - 2, 4);
    P1_ITER(NT - 1, 0);

    // ---- combine the 4 waves; reuse lbuf (all staging drained) ------------
    __syncthreads();
    if (lane == 0) { red_m[w] = m; red_l[w] = l; }
    __syncthreads();

    const float M = fmaxf(fmaxf(red_m[0], red_m[1]), fmaxf(red_m[2], red_m[3]));
    const float sc = __expf(m - M);
    float4* accbuf = lbuf;
#pragma unroll
    for (int j = 0; j < 4; ++j) {
        float4 a = acc[j];
        accbuf[w * 256 + lane + 64 * j] =
            make_float4(a.x * sc, a.y * sc, a.z * sc, a.w * sc);
    }
    __syncthreads();

    const float L = red_l[0] * __expf(red_m[0] - M)
                  + red_l[1] * __expf(red_m[1] - M)
                  + red_l[2] * __expf(red_m[2] - M)
                  + red_l[3] * __expf(red_m[3] - M);

    float* part = ws + (size_t)(b * NSPLIT + c) * PSTRIDE;
    float4 s4 = accbuf[tid];
    {
        float4 t1 = accbuf[256 + tid];
        float4 t2 = accbuf[512 + tid];
        float4 t3 = accbuf[768 + tid];
        s4.x += t1.x + t2.x + t3.x;
        s4.y += t1.y + t2.y + t3.y;
        s4.z += t1.z + t2.z + t3.z;
        s4.w += t1.w + t2.w + t3.w;
    }
    reinterpret_cast<float4*>(part)[tid] = s4;
    if (tid == 0) { part[H] = M; part[H + 1] = L; }
}

// ---------------- Pass 2: merge NSPLIT partials per batch -------------------
// Grid (B, 4): block merges one quarter (256 floats) of one batch's attn.
// Partials are L2/L3-hot (just written by pass1); latency-bound -> 4x blocks.
__global__ __launch_bounds__(256) void attn_pass2(
    const float* __restrict__ ws, float* __restrict__ attn)
{
    const int b   = blockIdx.x;
    const int q   = blockIdx.y;          // quarter 0..3
    const int tid = threadIdx.x;         // 0..255
    const int h   = q * 256 + tid;       // float index within attn row

    __shared__ float sm[NSPLIT];
    __shared__ float sl[NSPLIT];
    if (tid < NSPLIT) {
        const float* part = ws + (size_t)(b * NSPLIT + tid) * PSTRIDE;
        sm[tid] = part[H];
        sl[tid] = part[H + 1];
    }
    __syncthreads();

    float M = -INFINITY;
#pragma unroll
    for (int i = 0; i < NSPLIT; ++i) M = fmaxf(M, sm[i]);
    float L = 0.0f;
#pragma unroll
    for (int i = 0; i < NSPLIT; ++i) L = fmaf(sl[i], __expf(sm[i] - M), L);
    const float inv = 1.0f / L;

    float a = 0.0f;
#pragma unroll
    for (int i = 0; i < NSPLIT; ++i) {
        const float f = __expf(sm[i] - M);   // recompute: no scratch array
        a = fmaf(ws[(size_t)(b * NSPLIT + i) * PSTRIDE + h], f, a);
    }
    attn[(size_t)b * H + h] = a * inv;
}

// ---------------- Pass 3: out = [hidden, attn] @ W^T + bias -----------------
// Grid (H/16, 8): wave = 2 features, block handles 8 batches -> 512 blocks,
// all CUs busy; W re-read 8x (64 MB, L3-absorbed). Coalesced X reads.
__global__ __launch_bounds__(512) void attn_pass3(
    const float* __restrict__ hidden,
    const float* __restrict__ W,        // [H, 2H] row-major
    const float* __restrict__ bias,
    const float* __restrict__ attn,     // [B, H]
    float* __restrict__ out)            // [B, H]
{
    const int tid  = threadIdx.x;
    const int wid  = tid >> 6;
    const int lane = tid & 63;
    const int o0   = blockIdx.x * 16 + wid * 2;
    const int o1   = o0 + 1;
    const int blo  = blockIdx.y * (B / 8);
    const int bhi  = blo + (B / 8);

    const float4* W0 = reinterpret_cast<const float4*>(W + (size_t)o0 * (2 * H));
    const float4* W1 = reinterpret_cast<const float4*>(W + (size_t)o1 * (2 * H));
    float4 w0[8], w1[8];
#pragma unroll
    for (int j = 0; j < 8; ++j) w0[j] = W0[lane + 64 * j];
#pragma unroll
    for (int j = 0; j < 8; ++j) w1[j] = W1[lane + 64 * j];
    const float b0 = bias[o0];
    const float b1 = bias[o1];

    for (int b = blo; b < bhi; ++b) {
        const float4* h4 = reinterpret_cast<const float4*>(hidden + (size_t)b * H);
        const float4* a4 = reinterpret_cast<const float4*>(attn + (size_t)b * H);
        float s0 = 0.f, s1 = 0.f, t0 = 0.f, t1 = 0.f;
#pragma unroll
        for (int j = 0; j < 4; ++j) {
            float4 x = h4[lane + 64 * j];
            s0 = fmaf(x.x, w0[j].x, s0); s0 = fmaf(x.y, w0[j].y, s0);
            s0 = fmaf(x.z, w0[j].z, s0); s0 = fmaf(x.w, w0[j].w, s0);
            s1 = fmaf(x.x, w1[j].x, s1); s1 = fmaf(x.y, w1[j].y, s1);
            s1 = fmaf(x.z, w1[j].z, s1); s1 = fmaf(x.w, w1[j].w, s1);
            float4 y = a4[lane + 64 * j];
            t0 = fmaf(y.x, w0[j + 4].x, t0); t0 = fmaf(y.y, w0[j + 4].y, t0);
            t0 = fmaf(y.z, w0[j + 4].z, t0); t0 = fmaf(y.w, w0[j + 4].w, t0);
            t1 = fmaf(y.x, w1[j + 4].x, t1); t1 = fmaf(y.y, w1[j + 4].y, t1);
            t1 = fmaf(y.z, w1[j + 4].z, t1); t1 = fmaf(y.w, w1[j + 4].w, t1);
        }
        s0 += t0; s1 += t1;
#pragma unroll
        for (int off = 32; off >= 1; off >>= 1) {
            s0 += __shfl_xor(s0, off);
            s1 += __shfl_xor(s1, off);
        }
        if (lane == 0) {
            out[(size_t)b * H + o0] = s0 + b0;
            out[(size_t)b * H + o1] = s1 + b1;
        }
    }
}

extern "C" void kernel_launch(void* const* d_in, const int* in_sizes, int n_in,
                              void* d_out, int out_size, void* d_ws, size_t ws_size,
                              hipStream_t stream)
{
    const float* lstm   = (const float*)d_in[0];  // [B,S,H]
    const float* hidden = (const float*)d_in[1];  // [B,H]
    const float* W      = (const float*)d_in[2];  // [H,2H]
    const float* bias   = (const float*)d_in[3];  // [H]
    float* out = (float*)d_out;                   // [B,H]
    float* ws  = (float*)d_ws;                    // ~4.5 MB used
    float* attn = ws + ATTN_OFF;

    attn_pass1<<<dim3(NSPLIT, B), 256, 0, stream>>>(lstm, hidden, ws);
    attn_pass2<<<dim3(B, 4), 256, 0, stream>>>(ws, attn);
    attn_pass3<<<dim3(H / 16, 8), 512, 0, stream>>>(hidden, W, bias, attn, out);
}